// Round 1
// baseline (187.542 us; speedup 1.0000x reference)
//
#include <hip/hip_runtime.h>
#include <stdint.h>

#define DCH 64        // feature dim
#define KC 512        // codebook entries
#define KCHUNK 128    // codes staged in LDS per chunk
#define BLOCK 256
#define HWSZ 4096     // 64*64 spatial

// numpy pairwise_sum replication for 64 squared terms (fp-contract OFF so
// products round like numpy's elementwise multiply before pairwise add).
__device__ __forceinline__ float pairwise_sq64(const float* __restrict__ a) {
#pragma clang fp contract(off)
  float r0 = a[0] * a[0];
  float r1 = a[1] * a[1];
  float r2 = a[2] * a[2];
  float r3 = a[3] * a[3];
  float r4 = a[4] * a[4];
  float r5 = a[5] * a[5];
  float r6 = a[6] * a[6];
  float r7 = a[7] * a[7];
#pragma unroll
  for (int i = 8; i < 64; i += 8) {
    r0 = r0 + a[i + 0] * a[i + 0];
    r1 = r1 + a[i + 1] * a[i + 1];
    r2 = r2 + a[i + 2] * a[i + 2];
    r3 = r3 + a[i + 3] * a[i + 3];
    r4 = r4 + a[i + 4] * a[i + 4];
    r5 = r5 + a[i + 5] * a[i + 5];
    r6 = r6 + a[i + 6] * a[i + 6];
    r7 = r7 + a[i + 7] * a[i + 7];
  }
  return ((r0 + r1) + (r2 + r3)) + ((r4 + r5) + (r6 + r7));
}

__global__ __launch_bounds__(BLOCK) void vq_argmin_kernel(
    const float* __restrict__ Z,   // (32, 64, 64, 64) = (B, D, H, W)
    const float* __restrict__ W,   // (512, 64)
    int* __restrict__ out,         // (B*H*W) int32 indices
    int npos) {
  __shared__ float wlds[KCHUNK * DCH];  // 32 KB chunk of codebook
  __shared__ float wnorm[KC];           // 2 KB per-code squared norms

  const int tid = threadIdx.x;
  const int n = blockIdx.x * BLOCK + tid;
  const bool active = (n < npos);

  // ---- per-code squared norms, numpy pairwise order ----
  for (int c = tid; c < KC; c += BLOCK) {
    wnorm[c] = pairwise_sq64(W + c * DCH);
  }

  // ---- load this position's feature vector into registers ----
  // n -> (b, hw): channel stride is HWSZ floats.
  float z[DCH];
  if (active) {
    const int b = n >> 12;       // n / 4096
    const int hw = n & 4095;     // n % 4096
    const float* zbase = Z + ((size_t)b * DCH) * HWSZ + hw;
#pragma unroll
    for (int d = 0; d < DCH; ++d) z[d] = zbase[(size_t)d * HWSZ];
  } else {
#pragma unroll
    for (int d = 0; d < DCH; ++d) z[d] = 0.0f;
  }

  const float znorm = pairwise_sq64(z);

  float bmin = 3.4e38f;
  int bidx = 0;

  for (int ch = 0; ch < KC / KCHUNK; ++ch) {
    __syncthreads();
    // stage 128 codes (32 KB, contiguous) into LDS as float4
    {
      const float4* src = (const float4*)(W + (size_t)ch * KCHUNK * DCH);
      float4* dst = (float4*)wlds;
#pragma unroll
      for (int i = 0; i < (KCHUNK * DCH / 4) / BLOCK; ++i)
        dst[tid + i * BLOCK] = src[tid + i * BLOCK];
    }
    __syncthreads();

#pragma unroll 1
    for (int kk = 0; kk < KCHUNK; kk += 4) {
      const float* w0 = &wlds[(kk + 0) * DCH];
      const float* w1 = &wlds[(kk + 1) * DCH];
      const float* w2 = &wlds[(kk + 2) * DCH];
      const float* w3 = &wlds[(kk + 3) * DCH];
      float d0 = 0.0f, d1 = 0.0f, d2 = 0.0f, d3 = 0.0f;
#pragma unroll
      for (int d = 0; d < DCH; ++d) {
        const float zd = z[d];
        d0 = fmaf(zd, w0[d], d0);
        d1 = fmaf(zd, w1[d], d1);
        d2 = fmaf(zd, w2[d], d2);
        d3 = fmaf(zd, w3[d], d3);
      }
      const int kbase = ch * KCHUNK + kk;
      // exact reference order: (znorm - 2*dot) + wnorm  (2*dot is exact)
      const float dist0 = (znorm - 2.0f * d0) + wnorm[kbase + 0];
      const float dist1 = (znorm - 2.0f * d1) + wnorm[kbase + 1];
      const float dist2 = (znorm - 2.0f * d2) + wnorm[kbase + 2];
      const float dist3 = (znorm - 2.0f * d3) + wnorm[kbase + 3];
      // ascending-k scan with strict < == np.argmin first-min-wins
      if (dist0 < bmin) { bmin = dist0; bidx = kbase + 0; }
      if (dist1 < bmin) { bmin = dist1; bidx = kbase + 1; }
      if (dist2 < bmin) { bmin = dist2; bidx = kbase + 2; }
      if (dist3 < bmin) { bmin = dist3; bidx = kbase + 3; }
    }
  }

  if (active) out[n] = bidx;
}

extern "C" void kernel_launch(void* const* d_in, const int* in_sizes, int n_in,
                              void* d_out, int out_size, void* d_ws, size_t ws_size,
                              hipStream_t stream) {
  const float* Z = (const float*)d_in[0];  // (32,64,64,64) fp32
  const float* W = (const float*)d_in[1];  // (512,64) fp32
  int* out = (int*)d_out;                  // int32 indices, B*H*W

  const int npos = in_sizes[0] / DCH;      // 131072
  const int grid = (npos + BLOCK - 1) / BLOCK;
  vq_argmin_kernel<<<grid, BLOCK, 0, stream>>>(Z, W, out, npos);
}